// Round 5
// baseline (278.927 us; speedup 1.0000x reference)
//
#include <hip/hip_runtime.h>
#include <math.h>

// ---------------------------------------------------------------------------
// HADCommNetwork forward — zero-LDS direct-register MFMA version.
// B=64, N=512, OBS=128, H=256, M=128, ACT=16, T=32768.
// All GEMM-shaped kernels: NT MFMA (16x16x32 bf16), tile 32 rows x 256 cols,
// 4 waves each owning a 64-col quarter; operands loaded global->register
// (everything is L2-resident), NO LDS staging, NO barriers in K-loops.
// 7 launches: prep_w | prep_obs | enc(+imp) | msg|q | k|v | flash3 | x+heads
// ---------------------------------------------------------------------------

typedef __attribute__((ext_vector_type(8))) short short8;
typedef __attribute__((ext_vector_type(4))) float f32x4;

#define RSQRT_D 0.08838834764831843f  // 1/sqrt(128)
#define MFMA __builtin_amdgcn_mfma_f32_16x16x32_bf16

__device__ __forceinline__ unsigned short f2bf(float f) {
  union { float f; unsigned u; } v; v.f = f;
  return (unsigned short)((v.u + 0x7FFFu + ((v.u >> 16) & 1u)) >> 16);
}
__device__ __forceinline__ float bf2f(unsigned short h) {
  union { unsigned u; float f; } v; v.u = ((unsigned)h) << 16;
  return v.f;
}
__device__ __forceinline__ unsigned pack2(float a, float b) {
  return (unsigned)f2bf(a) | ((unsigned)f2bf(b) << 16);
}
__device__ __forceinline__ short8 ld8(const unsigned short* p) {
  return *(const short8*)p;
}

// ---------------- consolidated weight prep ----------------
__global__ __launch_bounds__(256) void prep_w(
    const float* __restrict__ We, const float* __restrict__ Wq,
    const float* __restrict__ Wk, const float* __restrict__ Wv,
    const float* __restrict__ Wp, const float* __restrict__ Wc,
    const float* __restrict__ Wn, const float* __restrict__ Wb,
    const float* __restrict__ bc, const float* __restrict__ bn,
    const float* __restrict__ bb, const float* __restrict__ Wa,
    const float* __restrict__ Wcr, unsigned short* __restrict__ WeT,
    unsigned short* __restrict__ Wmq, unsigned short* __restrict__ Wkv,
    unsigned short* __restrict__ WpT, unsigned short* __restrict__ WaCrT,
    float* __restrict__ bm) {
  int idx = blockIdx.x * 256 + threadIdx.x;
  if (idx < 32768) {                 // WeT[n 256][k 128]
    int n = idx >> 7, k = idx & 127;
    WeT[idx] = f2bf(We[k * 256 + n]);
  } else if (idx < 65536) {          // Wmq rows 0..127: WmT[d 128][h 256]
    int i = idx - 32768;
    int d = i >> 8, h = i & 255;
    float v = (d < 32)   ? Wc[h * 32 + d]
            : (d < 96)   ? Wn[h * 64 + (d - 32)]
                         : Wb[h * 32 + (d - 96)];
    Wmq[i] = f2bf(v);
  } else if (idx < 98304) {          // Wmq rows 128..255: WqT[n 128][k 256]
    int i = idx - 65536;
    int n = i >> 8, k = i & 255;
    Wmq[32768 + i] = f2bf(Wq[k * 128 + n]);
  } else if (idx < 114688) {         // Wkv rows 0..127: WkT[128][128]
    int i = idx - 98304;
    int n = i >> 7, k = i & 127;
    Wkv[i] = f2bf(Wk[k * 128 + n]);
  } else if (idx < 131072) {         // Wkv rows 128..255: WvT[128][128]
    int i = idx - 114688;
    int n = i >> 7, k = i & 127;
    Wkv[16384 + i] = f2bf(Wv[k * 128 + n]);
  } else if (idx < 229376) {         // WpT[n 256][k 384]
    int i = idx - 131072;
    int n = i / 384, k = i - n * 384;
    WpT[i] = f2bf(Wp[k * 256 + n]);
  } else if (idx < 237568) {         // WaCrT[32][256]: 0..15 Wa^T, 16 Wcr^T
    int i = idx - 229376;
    int n = i >> 8, k = i & 255;
    float v = (n < 16) ? Wa[k * 16 + n] : (n == 16) ? Wcr[k] : 0.f;
    WaCrT[i] = f2bf(v);
  } else if (idx < 237696) {         // bm
    int i = idx - 237568;
    bm[i] = (i < 32) ? bc[i] : (i < 96) ? bn[i - 32] : bb[i - 96];
  }
}

// ---------------- obs prep: norms + bf16 conversions ----------------
__global__ __launch_bounds__(256) void prep_obs(
    const float* __restrict__ obs, unsigned short* __restrict__ obs_bf,
    unsigned short* __restrict__ As, unsigned short* __restrict__ Bs) {
  int t = blockIdx.x * 4 + (threadIdx.x >> 6);
  int lane = threadIdx.x & 63;
  const float* row = obs + (size_t)t * 128;
  float2 o = *(const float2*)(row + lane * 2);
  float s2 = o.x * o.x + o.y * o.y;
#pragma unroll
  for (int off = 1; off < 64; off <<= 1) s2 += __shfl_xor(s2, off);
  float inv = 1.f / (sqrtf(s2) + 1e-8f);
  ((unsigned*)obs_bf)[(size_t)t * 64 + lane] = pack2(o.x, o.y);
  ((unsigned*)As)[(size_t)t * 128 + 64 + lane] =
      pack2(o.x * 0.5f * inv, o.y * 0.5f * inv);
  ((unsigned*)Bs)[(size_t)t * 128 + 64 + lane] = pack2(o.x * inv, o.y * inv);
}

// ---------------- enc = relu(obs @ We + be), fused importance ----------------
// 1024 blocks of 32 tokens. Wave w owns output cols [w*64, w*64+64).
__global__ __launch_bounds__(256) void enc_gemm(
    const unsigned short* __restrict__ obs_bf,
    const unsigned short* __restrict__ WeT, const float* __restrict__ be,
    const float* __restrict__ Wi, const float* __restrict__ bi,
    unsigned short* __restrict__ enc, float* __restrict__ impA,
    float* __restrict__ impB) {
  __shared__ float ired[4][32];
  const int tid = threadIdx.x, lane = tid & 63, wave = tid >> 6;
  const int quad = lane >> 4, l16 = lane & 15;
  const int bm = blockIdx.x * 32;
  f32x4 acc[2][4];
#pragma unroll
  for (int i = 0; i < 2; ++i)
#pragma unroll
    for (int j = 0; j < 4; ++j) acc[i][j] = (f32x4){0.f, 0.f, 0.f, 0.f};
#pragma unroll
  for (int kc = 0; kc < 4; ++kc) {
    short8 af[2], bf[4];
#pragma unroll
    for (int i = 0; i < 2; ++i)
      af[i] = ld8(obs_bf + (size_t)(bm + i * 16 + l16) * 128 + kc * 32 + quad * 8);
#pragma unroll
    for (int j = 0; j < 4; ++j)
      bf[j] = ld8(WeT + (size_t)(wave * 64 + j * 16 + l16) * 128 + kc * 32 + quad * 8);
#pragma unroll
    for (int i = 0; i < 2; ++i)
#pragma unroll
      for (int j = 0; j < 4; ++j) acc[i][j] = MFMA(af[i], bf[j], acc[i][j], 0, 0, 0);
  }
  float ip[2][4];
#pragma unroll
  for (int i = 0; i < 2; ++i)
#pragma unroll
    for (int r = 0; r < 4; ++r) ip[i][r] = 0.f;
#pragma unroll
  for (int i = 0; i < 2; ++i)
#pragma unroll
    for (int j = 0; j < 4; ++j) {
      const int col = wave * 64 + j * 16 + l16;
      const float bv = be[col], wv = Wi[col];
      const int rowb = bm + i * 16 + quad * 4;
#pragma unroll
      for (int r = 0; r < 4; ++r) {
        float v = fmaxf(acc[i][j][r] + bv, 0.f);
        enc[(size_t)(rowb + r) * 256 + col] = f2bf(v);
        ip[i][r] += v * wv;
      }
    }
#pragma unroll
  for (int i = 0; i < 2; ++i)
#pragma unroll
    for (int r = 0; r < 4; ++r) {
#pragma unroll
      for (int off = 1; off < 16; off <<= 1)
        ip[i][r] += __shfl_xor(ip[i][r], off);
    }
  if (l16 == 0) {
#pragma unroll
    for (int i = 0; i < 2; ++i)
#pragma unroll
      for (int r = 0; r < 4; ++r)
        ired[wave][i * 16 + quad * 4 + r] = ip[i][r];
  }
  __syncthreads();
  if (tid < 32) {
    float s = ired[0][tid] + ired[1][tid] + ired[2][tid] + ired[3][tid] + bi[0];
    float sg = 1.0f / (1.0f + __expf(-s));
    impA[bm + tid] = sg * RSQRT_D;
    impB[bm + tid] = sg;
  }
}

// ---------------- msg | q(scaled into As) ----------------
__global__ __launch_bounds__(256) void msgq_gemm(
    const unsigned short* __restrict__ enc, const unsigned short* __restrict__ Wmq,
    const float* __restrict__ bm, const float* __restrict__ bq,
    const float* __restrict__ impA, unsigned short* __restrict__ msg,
    unsigned short* __restrict__ As) {
  const int tid = threadIdx.x, lane = tid & 63, wave = tid >> 6;
  const int quad = lane >> 4, l16 = lane & 15;
  const int bmr = blockIdx.x * 32;
  f32x4 acc[2][4];
#pragma unroll
  for (int i = 0; i < 2; ++i)
#pragma unroll
    for (int j = 0; j < 4; ++j) acc[i][j] = (f32x4){0.f, 0.f, 0.f, 0.f};
#pragma unroll
  for (int kc = 0; kc < 8; ++kc) {
    short8 af[2], bf[4];
#pragma unroll
    for (int i = 0; i < 2; ++i)
      af[i] = ld8(enc + (size_t)(bmr + i * 16 + l16) * 256 + kc * 32 + quad * 8);
#pragma unroll
    for (int j = 0; j < 4; ++j)
      bf[j] = ld8(Wmq + (size_t)(wave * 64 + j * 16 + l16) * 256 + kc * 32 + quad * 8);
#pragma unroll
    for (int i = 0; i < 2; ++i)
#pragma unroll
      for (int j = 0; j < 4; ++j) acc[i][j] = MFMA(af[i], bf[j], acc[i][j], 0, 0, 0);
  }
#pragma unroll
  for (int i = 0; i < 2; ++i) {
    const int rowb = bmr + i * 16 + quad * 4;
#pragma unroll
    for (int j = 0; j < 4; ++j) {
      const int col = wave * 64 + j * 16 + l16;
      if (col < 128) {
        const float bv = bm[col];
#pragma unroll
        for (int r = 0; r < 4; ++r)
          msg[(size_t)(rowb + r) * 128 + col] = f2bf(acc[i][j][r] + bv);
      } else {
        const int c = col - 128;
        const float bv = bq[c];
#pragma unroll
        for (int r = 0; r < 4; ++r)
          As[(size_t)(rowb + r) * 256 + c] =
              f2bf((acc[i][j][r] + bv) * impA[rowb + r]);
      }
    }
  }
}

// ---------------- k(scaled into Bs) | v(transposed into vT) ----------------
__global__ __launch_bounds__(256) void kv_gemm(
    const unsigned short* __restrict__ msg, const unsigned short* __restrict__ Wkv,
    const float* __restrict__ bk, const float* __restrict__ bv,
    const float* __restrict__ impB, unsigned short* __restrict__ Bs,
    unsigned short* __restrict__ vT) {
  const int tid = threadIdx.x, lane = tid & 63, wave = tid >> 6;
  const int quad = lane >> 4, l16 = lane & 15;
  const int bmr = blockIdx.x * 32;
  f32x4 acc[2][4];
#pragma unroll
  for (int i = 0; i < 2; ++i)
#pragma unroll
    for (int j = 0; j < 4; ++j) acc[i][j] = (f32x4){0.f, 0.f, 0.f, 0.f};
#pragma unroll
  for (int kc = 0; kc < 4; ++kc) {
    short8 af[2], bf[4];
#pragma unroll
    for (int i = 0; i < 2; ++i)
      af[i] = ld8(msg + (size_t)(bmr + i * 16 + l16) * 128 + kc * 32 + quad * 8);
#pragma unroll
    for (int j = 0; j < 4; ++j)
      bf[j] = ld8(Wkv + (size_t)(wave * 64 + j * 16 + l16) * 128 + kc * 32 + quad * 8);
#pragma unroll
    for (int i = 0; i < 2; ++i)
#pragma unroll
      for (int j = 0; j < 4; ++j) acc[i][j] = MFMA(af[i], bf[j], acc[i][j], 0, 0, 0);
  }
#pragma unroll
  for (int i = 0; i < 2; ++i) {
    const int rowb = bmr + i * 16 + quad * 4;
#pragma unroll
    for (int j = 0; j < 4; ++j) {
      const int col = wave * 64 + j * 16 + l16;
      if (col < 128) {
        const float bvv = bk[col];
#pragma unroll
        for (int r = 0; r < 4; ++r)
          Bs[(size_t)(rowb + r) * 256 + col] =
              f2bf((acc[i][j][r] + bvv) * impB[rowb + r]);
      } else {
        const int c = col - 128;
        const float bvv = bv[c];
        uint2 o;
        o.x = pack2(acc[i][j][0] + bvv, acc[i][j][1] + bvv);
        o.y = pack2(acc[i][j][2] + bvv, acc[i][j][3] + bvv);
        *(uint2*)(vT + ((size_t)(rowb >> 9) * 128 + c) * 512 + (rowb & 511)) = o;
      }
    }
  }
}

// ---------------- flash v3: zero-LDS QK, wave-owned key quarters ----------------
// 1024 blocks: b = id&63 (XCD-local), qt = id>>6 (Q-tile 32). Wave w owns keys
// [w*128, w*128+128): QK has NO barriers. Exact softmax (2 barriers), P via one
// LDS round-trip, PV reads vT direct (wave w owns d-cols [w*32, w*32+32)).
__global__ __launch_bounds__(256) void flash3(
    const unsigned short* __restrict__ As, const unsigned short* __restrict__ Bs,
    const unsigned short* __restrict__ vT, unsigned short* __restrict__ agg) {
  __shared__ unsigned short Pp[32 * 520];
  __shared__ float redm[4][32];
  __shared__ float reds[4][32];
  const int tid = threadIdx.x, lane = tid & 63, wave = tid >> 6;
  const int quad = lane >> 4, l16 = lane & 15;
  const int b = blockIdx.x & 63;
  const int qt = blockIdx.x >> 6;
  const size_t tok0 = (size_t)b * 512 + qt * 32;

  f32x4 s[2][8];
#pragma unroll
  for (int i = 0; i < 2; ++i)
#pragma unroll
    for (int nt = 0; nt < 8; ++nt) s[i][nt] = (f32x4){0.f, 0.f, 0.f, 0.f};

  // ---- QK^T: wave's 128 keys, K=256, no barriers ----
#pragma unroll
  for (int kc = 0; kc < 8; ++kc) {
    short8 af[2];
#pragma unroll
    for (int i = 0; i < 2; ++i)
      af[i] = ld8(As + (tok0 + i * 16 + l16) * 256 + kc * 32 + quad * 8);
#pragma unroll
    for (int nt = 0; nt < 8; ++nt) {
      short8 bf = ld8(Bs + ((size_t)b * 512 + wave * 128 + nt * 16 + l16) * 256 +
                      kc * 32 + quad * 8);
#pragma unroll
      for (int i = 0; i < 2; ++i) s[i][nt] = MFMA(af[i], bf, s[i][nt], 0, 0, 0);
    }
  }

  // ---- exact softmax ----
  float mt[2][4];
#pragma unroll
  for (int i = 0; i < 2; ++i)
#pragma unroll
    for (int r = 0; r < 4; ++r) {
      float mv = -1e30f;
#pragma unroll
      for (int nt = 0; nt < 8; ++nt) mv = fmaxf(mv, s[i][nt][r]);
#pragma unroll
      for (int off = 1; off < 16; off <<= 1) mv = fmaxf(mv, __shfl_xor(mv, off));
      mt[i][r] = mv;
    }
  if (l16 == 0) {
#pragma unroll
    for (int i = 0; i < 2; ++i)
#pragma unroll
      for (int r = 0; r < 4; ++r) redm[wave][i * 16 + quad * 4 + r] = mt[i][r];
  }
  __syncthreads();
  float lsum[2][4];
#pragma unroll
  for (int i = 0; i < 2; ++i)
#pragma unroll
    for (int r = 0; r < 4; ++r) {
      const int row = i * 16 + quad * 4 + r;
      float mfull = fmaxf(fmaxf(redm[0][row], redm[1][row]),
                          fmaxf(redm[2][row], redm[3][row]));
      float sum = 0.f;
#pragma unroll
      for (int nt = 0; nt < 8; ++nt) {
        float p = __expf(s[i][nt][r] - mfull);
        s[i][nt][r] = p;
        sum += p;
      }
#pragma unroll
      for (int off = 1; off < 16; off <<= 1) sum += __shfl_xor(sum, off);
      lsum[i][r] = sum;
    }
  if (l16 == 0) {
#pragma unroll
    for (int i = 0; i < 2; ++i)
#pragma unroll
      for (int r = 0; r < 4; ++r) reds[wave][i * 16 + quad * 4 + r] = lsum[i][r];
  }
  // P tile -> LDS (A-operand layout), cols = wave's 128 keys
#pragma unroll
  for (int i = 0; i < 2; ++i)
#pragma unroll
    for (int nt = 0; nt < 8; ++nt) {
      const int col = wave * 128 + nt * 16 + l16;
#pragma unroll
      for (int r = 0; r < 4; ++r)
        Pp[(i * 16 + quad * 4 + r) * 520 + col] = f2bf(s[i][nt][r]);
    }
  __syncthreads();
  float linv[2][4];
#pragma unroll
  for (int i = 0; i < 2; ++i)
#pragma unroll
    for (int r = 0; r < 4; ++r) {
      const int row = i * 16 + quad * 4 + r;
      linv[i][r] =
          1.0f / (reds[0][row] + reds[1][row] + reds[2][row] + reds[3][row]);
    }

  // ---- PV: O[32 q][d in wave*32..+32), K=512, vT direct ----
  f32x4 o[2][2];
#pragma unroll
  for (int i = 0; i < 2; ++i)
#pragma unroll
    for (int j = 0; j < 2; ++j) o[i][j] = (f32x4){0.f, 0.f, 0.f, 0.f};
#pragma unroll
  for (int kc = 0; kc < 16; ++kc) {
    short8 pa[2];
#pragma unroll
    for (int i = 0; i < 2; ++i)
      pa[i] = *(const short8*)&Pp[(i * 16 + l16) * 520 + kc * 32 + quad * 8];
#pragma unroll
    for (int j = 0; j < 2; ++j) {
      short8 vb = ld8(vT + ((size_t)b * 128 + wave * 32 + j * 16 + l16) * 512 +
                      kc * 32 + quad * 8);
#pragma unroll
      for (int i = 0; i < 2; ++i) o[i][j] = MFMA(pa[i], vb, o[i][j], 0, 0, 0);
    }
  }
#pragma unroll
  for (int i = 0; i < 2; ++i) {
    const size_t rowb = tok0 + i * 16 + quad * 4;
#pragma unroll
    for (int j = 0; j < 2; ++j) {
      const int col = wave * 32 + j * 16 + l16;
#pragma unroll
      for (int r = 0; r < 4; ++r)
        agg[(rowb + r) * 128 + col] = f2bf(o[i][j][r] * linv[i][r]);
    }
  }
}

// ---------------- fused x-GEMM + heads ----------------
__global__ __launch_bounds__(256) void xh_gemm(
    const unsigned short* __restrict__ enc, const unsigned short* __restrict__ agg,
    const unsigned short* __restrict__ WpT, const float* __restrict__ bp,
    const unsigned short* __restrict__ WaCrT, const float* __restrict__ ba,
    const float* __restrict__ bcr, float* __restrict__ logits,
    float* __restrict__ value) {
  __shared__ unsigned short xs[32][264];
  const int tid = threadIdx.x, lane = tid & 63, wave = tid >> 6;
  const int quad = lane >> 4, l16 = lane & 15;
  const int bm = blockIdx.x * 32;
  f32x4 acc[2][4];
#pragma unroll
  for (int i = 0; i < 2; ++i)
#pragma unroll
    for (int j = 0; j < 4; ++j) acc[i][j] = (f32x4){0.f, 0.f, 0.f, 0.f};
#pragma unroll
  for (int kc = 0; kc < 12; ++kc) {
    const unsigned short* A;
    int lda, ko;
    if (kc < 8) { A = enc; lda = 256; ko = kc * 32; }
    else        { A = agg; lda = 128; ko = (kc - 8) * 32; }
    short8 af[2], bf[4];
#pragma unroll
    for (int i = 0; i < 2; ++i)
      af[i] = ld8(A + (size_t)(bm + i * 16 + l16) * lda + ko + quad * 8);
#pragma unroll
    for (int j = 0; j < 4; ++j)
      bf[j] = ld8(WpT + (size_t)(wave * 64 + j * 16 + l16) * 384 + kc * 32 + quad * 8);
#pragma unroll
    for (int i = 0; i < 2; ++i)
#pragma unroll
      for (int j = 0; j < 4; ++j) acc[i][j] = MFMA(af[i], bf[j], acc[i][j], 0, 0, 0);
  }
#pragma unroll
  for (int i = 0; i < 2; ++i) {
    const int row = i * 16 + quad * 4;
#pragma unroll
    for (int j = 0; j < 4; ++j) {
      const int col = wave * 64 + j * 16 + l16;
      const float bvv = bp[col];
#pragma unroll
      for (int r = 0; r < 4; ++r)
        xs[row + r][col] = f2bf(fmaxf(acc[i][j][r] + bvv, 0.f));
    }
  }
  __syncthreads();
  const int wm2 = wave & 1, wn2 = wave >> 1;
  f32x4 hacc = (f32x4){0.f, 0.f, 0.f, 0.f};
#pragma unroll
  for (int kk = 0; kk < 8; ++kk) {
    short8 pa = *(const short8*)&xs[wm2 * 16 + l16][kk * 32 + quad * 8];
    short8 wb = ld8(WaCrT + (size_t)(wn2 * 16 + l16) * 256 + kk * 32 + quad * 8);
    hacc = MFMA(pa, wb, hacc, 0, 0, 0);
  }
  const int n = wn2 * 16 + l16;
#pragma unroll
  for (int r = 0; r < 4; ++r) {
    const size_t tok = bm + wm2 * 16 + quad * 4 + r;
    if (n < 16)
      logits[tok * 16 + n] = hacc[r] + ba[n];
    else if (n == 16)
      value[tok] = hacc[r] + bcr[0];
  }
}

// ---------------------------------------------------------------------------
extern "C" void kernel_launch(void* const* d_in, const int* in_sizes, int n_in,
                              void* d_out, int out_size, void* d_ws,
                              size_t ws_size, hipStream_t stream) {
  const float* obs = (const float*)d_in[0];
  const float* We = (const float*)d_in[2];
  const float* be = (const float*)d_in[3];
  const float* Wc = (const float*)d_in[4];
  const float* bc = (const float*)d_in[5];
  const float* Wn = (const float*)d_in[6];
  const float* bn = (const float*)d_in[7];
  const float* Wb = (const float*)d_in[8];
  const float* bb = (const float*)d_in[9];
  const float* Wi = (const float*)d_in[10];
  const float* bi = (const float*)d_in[11];
  const float* Wq = (const float*)d_in[12];
  const float* bq = (const float*)d_in[13];
  const float* Wk = (const float*)d_in[14];
  const float* bk = (const float*)d_in[15];
  const float* Wv = (const float*)d_in[16];
  const float* bv = (const float*)d_in[17];
  const float* Wp = (const float*)d_in[18];
  const float* bp = (const float*)d_in[19];
  const float* Wa = (const float*)d_in[20];
  const float* ba = (const float*)d_in[21];
  const float* Wcr = (const float*)d_in[22];
  const float* bcr = (const float*)d_in[23];

  char* base = (char*)d_ws;
  unsigned short* enc_bf = (unsigned short*)(base);              // 16.78 MB
  unsigned short* As     = (unsigned short*)(base + 16777216);   // 16.78 MB
  unsigned short* Bs     = (unsigned short*)(base + 33554432);   // 16.78 MB
  unsigned short* obsagg = (unsigned short*)(base + 50331648);   // 8.39 MB (obs_bf -> agg)
  unsigned short* msg_bf = (unsigned short*)(base + 58720256);   // 8.39 MB
  unsigned short* vT     = (unsigned short*)(base + 75497472);   // 8.39 MB
  float* impA            = (float*)(base + 83886080);
  float* impB            = (float*)(base + 84017152);
  unsigned short* WeT    = (unsigned short*)(base + 84148224);   // 64 KB
  unsigned short* Wmq    = (unsigned short*)(base + 84213760);   // 128 KB
  unsigned short* Wkv    = (unsigned short*)(base + 84344832);   // 64 KB
  unsigned short* WpT    = (unsigned short*)(base + 84410368);   // 192 KB
  float* bmb             = (float*)(base + 84606976);            // 512 B
  unsigned short* WaCrT  = (unsigned short*)(base + 84607488);   // 16 KB

  prep_w<<<929, 256, 0, stream>>>(We, Wq, Wk, Wv, Wp, Wc, Wn, Wb, bc, bn, bb,
                                  Wa, Wcr, WeT, Wmq, Wkv, WpT, WaCrT, bmb);
  prep_obs<<<8192, 256, 0, stream>>>(obs, obsagg, As, Bs);

  enc_gemm<<<1024, 256, 0, stream>>>(obsagg, WeT, be, Wi, bi, enc_bf, impA,
                                     impB);
  msgq_gemm<<<1024, 256, 0, stream>>>(enc_bf, Wmq, bmb, bq, impA, msg_bf, As);
  kv_gemm<<<1024, 256, 0, stream>>>(msg_bf, Wkv, bk, bv, impB, Bs, vT);
  flash3<<<1024, 256, 0, stream>>>(As, Bs, vT, obsagg);
  xh_gemm<<<1024, 256, 0, stream>>>(enc_bf, obsagg, WpT, bp, WaCrT, ba, bcr,
                                    (float*)d_out, (float*)d_out + 524288);
}

// Round 6
// 199.657 us; speedup vs baseline: 1.3970x; 1.3970x over previous
//
#include <hip/hip_runtime.h>
#include <math.h>

// ---------------------------------------------------------------------------
// HADCommNetwork forward — async-staged MFMA version (global_load_lds w=16).
// B=64, N=512, OBS=128, H=256, M=128, ACT=16, T=32768.
// 6 launches: prep_all | enc(+imp atomics) | msg|q | k|v | flash4 | x+heads
// All LDS tiles are XOR-source-swizzled so ds_read_b128 fragments are
// conflict-free despite the DMA's no-padding constraint.
// ---------------------------------------------------------------------------

typedef __attribute__((ext_vector_type(8))) short short8;
typedef __attribute__((ext_vector_type(4))) float f32x4;

#define RSQRT_D 0.08838834764831843f  // 1/sqrt(128)
#define MFMA __builtin_amdgcn_mfma_f32_16x16x32_bf16

__device__ __forceinline__ unsigned short f2bf(float f) {
  union { float f; unsigned u; } v; v.f = f;
  return (unsigned short)((v.u + 0x7FFFu + ((v.u >> 16) & 1u)) >> 16);
}
__device__ __forceinline__ unsigned pack2(float a, float b) {
  return (unsigned)f2bf(a) | ((unsigned)f2bf(b) << 16);
}
__device__ __forceinline__ short8 ld8(const unsigned short* p) {
  return *(const short8*)p;
}
// async 16B global -> LDS (lds dest must be wave-uniform; HW adds lane*16)
__device__ __forceinline__ void gl16(const unsigned short* g,
                                     unsigned short* l) {
  __builtin_amdgcn_global_load_lds(
      (const __attribute__((address_space(1))) unsigned int*)(const void*)g,
      (__attribute__((address_space(3))) unsigned int*)(void*)l, 16, 0, 0);
}

// ---------------- prep: weights + obs + output init ----------------
__global__ __launch_bounds__(256) void prep_all(
    const float* __restrict__ obs, const float* __restrict__ We,
    const float* __restrict__ Wq, const float* __restrict__ Wk,
    const float* __restrict__ Wv, const float* __restrict__ Wp,
    const float* __restrict__ Wc, const float* __restrict__ Wn,
    const float* __restrict__ Wb, const float* __restrict__ bc,
    const float* __restrict__ bn, const float* __restrict__ bb,
    const float* __restrict__ Wa, const float* __restrict__ Wcr,
    const float* __restrict__ ba, const float* __restrict__ bcr,
    unsigned short* __restrict__ WeT, unsigned short* __restrict__ Wmq,
    unsigned short* __restrict__ Wkv, unsigned short* __restrict__ WpT,
    unsigned short* __restrict__ WaCrT, float* __restrict__ bm,
    unsigned short* __restrict__ obs_bf, unsigned short* __restrict__ As,
    unsigned short* __restrict__ Bs, float* __restrict__ logits,
    float* __restrict__ value, float* __restrict__ imp_raw) {
  const int bid = blockIdx.x, tid = threadIdx.x;
  if (bid < 929) {
    int idx = bid * 256 + tid;
    if (idx < 32768) {                 // WeT[n 256][k 128]
      int n = idx >> 7, k = idx & 127;
      WeT[idx] = f2bf(We[k * 256 + n]);
    } else if (idx < 65536) {          // Wmq rows 0..127: WmT[d 128][h 256]
      int i = idx - 32768;
      int d = i >> 8, h = i & 255;
      float v = (d < 32)   ? Wc[h * 32 + d]
              : (d < 96)   ? Wn[h * 64 + (d - 32)]
                           : Wb[h * 32 + (d - 96)];
      Wmq[i] = f2bf(v);
    } else if (idx < 98304) {          // Wmq rows 128..255: WqT[n 128][k 256]
      int i = idx - 65536;
      int n = i >> 8, k = i & 255;
      Wmq[32768 + i] = f2bf(Wq[k * 128 + n]);
    } else if (idx < 114688) {         // Wkv rows 0..127: WkT
      int i = idx - 98304;
      int n = i >> 7, k = i & 127;
      Wkv[i] = f2bf(Wk[k * 128 + n]);
    } else if (idx < 131072) {         // Wkv rows 128..255: WvT
      int i = idx - 114688;
      int n = i >> 7, k = i & 127;
      Wkv[16384 + i] = f2bf(Wv[k * 128 + n]);
    } else if (idx < 229376) {         // WpT[n 256][k 384]
      int i = idx - 131072;
      int n = i / 384, k = i - n * 384;
      WpT[i] = f2bf(Wp[k * 256 + n]);
    } else if (idx < 237568) {         // WaCrT[32][256]
      int i = idx - 229376;
      int n = i >> 8, k = i & 255;
      float v = (n < 16) ? Wa[k * 16 + n] : (n == 16) ? Wcr[k] : 0.f;
      WaCrT[i] = f2bf(v);
    } else if (idx < 237696) {
      int i = idx - 237568;
      bm[i] = (i < 32) ? bc[i] : (i < 96) ? bn[i - 32] : bb[i - 96];
    }
  } else if (bid < 9121) {
    int t = (bid - 929) * 4 + (tid >> 6);
    int lane = tid & 63;
    const float* row = obs + (size_t)t * 128;
    float2 o = *(const float2*)(row + lane * 2);
    float s2 = o.x * o.x + o.y * o.y;
#pragma unroll
    for (int off = 1; off < 64; off <<= 1) s2 += __shfl_xor(s2, off);
    float inv = 1.f / (sqrtf(s2) + 1e-8f);
    ((unsigned*)obs_bf)[(size_t)t * 64 + lane] = pack2(o.x, o.y);
    ((unsigned*)As)[(size_t)t * 128 + 64 + lane] =
        pack2(o.x * 0.5f * inv, o.y * 0.5f * inv);
    ((unsigned*)Bs)[(size_t)t * 128 + 64 + lane] = pack2(o.x * inv, o.y * inv);
  } else if (bid < 11297) {
    int i = (bid - 9121) * 256 + tid;  // 0..557055
    if (i < 524288) logits[i] = ba[i & 15];
    else value[i - 524288] = bcr[0];
  } else {
    imp_raw[(bid - 11297) * 256 + tid] = 0.f;
  }
}

// ---------------- epilogue element emit ----------------
// MODE: 0 bf16(+bias), 1 relu bf16, 2 bf16*(sigmoid scale), 3 vT transposed.
template <int MODE, int IMP>
__device__ __forceinline__ void emit(unsigned short* out, int ldc,
                                     const float* bias, const float* sg,
                                     int rowb, int col, const f32x4& a,
                                     float* ip, const float* Wi, int gcol) {
  const float bv = bias[col];
  if constexpr (MODE == 3) {
    uint2 o;
    o.x = pack2(a[0] + bv, a[1] + bv);
    o.y = pack2(a[2] + bv, a[3] + bv);
    *(uint2*)(out + ((size_t)(rowb >> 9) * 128 + col) * 512 + (rowb & 511)) = o;
  } else {
    float wv = 0.f;
    if constexpr (IMP) wv = Wi[gcol];
#pragma unroll
    for (int r = 0; r < 4; ++r) {
      float v = a[r] + bv;
      if constexpr (MODE == 1) v = fmaxf(v, 0.f);
      if constexpr (MODE == 2) v *= sg[r];
      out[(size_t)(rowb + r) * ldc + col] = f2bf(v);
      if constexpr (IMP) ip[r] += v * wv;
    }
  }
}

// ---------------- async-staged 128x128 NT MFMA GEMM ----------------
// grid (N/128, 32768/128). 4 waves, wave (wm,wn) computes 64x64.
// LDS rows are 64 shorts (128B, 8 x 16B chunks), source-swizzled by ^(row&7).
template <int M0, int M1, int IMP>
__global__ __launch_bounds__(256, 2) void gemm_t(
    const unsigned short* __restrict__ A1, int lda1, int K1,
    const unsigned short* __restrict__ A2, int lda2, int Ktot,
    const unsigned short* __restrict__ Bt, int ldb,
    const float* __restrict__ bias0, const float* __restrict__ bias1,
    const float* __restrict__ raw, const float* __restrict__ bi, float mult,
    const float* __restrict__ Wi, float* __restrict__ imp_out,
    unsigned short* __restrict__ out0, int ldc0,
    unsigned short* __restrict__ out1, int ldc1, int xsplit) {
  __shared__ unsigned short Asr[8192];
  __shared__ unsigned short Bsr[8192];
  const int tid = threadIdx.x, lane = tid & 63, wave = tid >> 6;
  const int quad = lane >> 4, l16 = lane & 15;
  const int wm = wave & 1, wn = wave >> 1;
  const int bm = blockIdx.y * 128, bn = blockIdx.x * 128;
  const int srow = tid >> 3, slc = tid & 7;

  f32x4 acc[4][4];
#pragma unroll
  for (int i = 0; i < 4; ++i)
#pragma unroll
    for (int j = 0; j < 4; ++j) acc[i][j] = (f32x4){0.f, 0.f, 0.f, 0.f};

  for (int kt = 0; kt < Ktot; kt += 64) {
    const unsigned short* Ap;
    int lda, kloc;
    if (kt < K1) { Ap = A1; lda = lda1; kloc = kt; }
    else         { Ap = A2; lda = lda2; kloc = kt - K1; }
#pragma unroll
    for (int i = 0; i < 4; ++i) {
      int row = i * 32 + srow;
      gl16(Ap + (size_t)(bm + row) * lda + kloc + ((slc ^ (row & 7)) << 3),
           Asr + i * 2048 + wave * 512);
      gl16(Bt + (size_t)(bn + row) * ldb + kt + ((slc ^ (row & 7)) << 3),
           Bsr + i * 2048 + wave * 512);
    }
    __syncthreads();
#pragma unroll
    for (int ks = 0; ks < 2; ++ks) {
      short8 af[4], bf[4];
#pragma unroll
      for (int mi = 0; mi < 4; ++mi) {
        int row = wm * 64 + mi * 16 + l16;
        af[mi] = *(const short8*)&Asr[row * 64 + (((ks * 4 + quad) ^ (row & 7)) << 3)];
      }
#pragma unroll
      for (int ni = 0; ni < 4; ++ni) {
        int row = wn * 64 + ni * 16 + l16;
        bf[ni] = *(const short8*)&Bsr[row * 64 + (((ks * 4 + quad) ^ (row & 7)) << 3)];
      }
#pragma unroll
      for (int mi = 0; mi < 4; ++mi)
#pragma unroll
        for (int ni = 0; ni < 4; ++ni)
          acc[mi][ni] = MFMA(af[mi], bf[ni], acc[mi][ni], 0, 0, 0);
    }
    __syncthreads();
  }

  float bi0 = 0.f;
  if constexpr (M0 == 2 || M1 == 2) bi0 = bi[0];
#pragma unroll
  for (int mi = 0; mi < 4; ++mi) {
    const int rowb = bm + wm * 64 + mi * 16 + quad * 4;
    float sg[4] = {0.f, 0.f, 0.f, 0.f};
    if constexpr (M0 == 2 || M1 == 2) {
#pragma unroll
      for (int r = 0; r < 4; ++r)
        sg[r] = mult / (1.f + __expf(-(raw[rowb + r] + bi0)));
    }
    float ip[4] = {0.f, 0.f, 0.f, 0.f};
#pragma unroll
    for (int ni = 0; ni < 4; ++ni) {
      const int col = bn + wn * 64 + ni * 16 + l16;
      if (col < xsplit)
        emit<M0, IMP>(out0, ldc0, bias0, sg, rowb, col, acc[mi][ni], ip, Wi, col);
      else
        emit<M1, 0>(out1, ldc1, bias1, sg, rowb, col - xsplit, acc[mi][ni],
                    nullptr, nullptr, 0);
    }
    if constexpr (IMP) {
#pragma unroll
      for (int r = 0; r < 4; ++r) {
#pragma unroll
        for (int off = 1; off < 16; off <<= 1)
          ip[r] += __shfl_xor(ip[r], off);
      }
      if (l16 == 0) {
#pragma unroll
        for (int r = 0; r < 4; ++r) atomicAdd(&imp_out[rowb + r], ip[r]);
      }
    }
  }
}

// ---------------- flash4: async-staged, single-pass softmax ----------------
// 1024 blocks: b = id&63, qt = id>>6 (Q-tile 32). Wave (wm,wn): 16q x 64keys.
// LDS rows 128 shorts (16 chunks), swizzle ^(row&15): conflict-free b128.
__global__ __launch_bounds__(256, 3) void flash4(
    const unsigned short* __restrict__ As, const unsigned short* __restrict__ Bs,
    const unsigned short* __restrict__ vT, unsigned short* __restrict__ agg) {
  __shared__ unsigned short Ub[16384];  // 32 KB
  __shared__ unsigned short Pp[4096];   // 8 KB
  __shared__ float redm[2][32];
  __shared__ float reds[2][32];
  const int tid = threadIdx.x, lane = tid & 63, wave = tid >> 6;
  const int quad = lane >> 4, l16 = lane & 15;
  const int wm = wave & 1, wn = wave >> 1;
  const int b = blockIdx.x & 63;
  const int qt = blockIdx.x >> 6;
  const size_t tok0 = (size_t)b * 512 + qt * 32;
  const int srow = tid >> 4, slc = tid & 15;

  short8 af[8];
#pragma unroll
  for (int kc = 0; kc < 8; ++kc)
    af[kc] = ld8(As + (tok0 + wm * 16 + l16) * 256 + kc * 32 + quad * 8);

  f32x4 s[4][4];
#pragma unroll
  for (int kt = 0; kt < 4; ++kt)
#pragma unroll
    for (int nt = 0; nt < 4; ++nt) s[kt][nt] = (f32x4){0.f, 0.f, 0.f, 0.f};

  // ---- QK^T ----
#pragma unroll
  for (int kt = 0; kt < 4; ++kt) {
#pragma unroll
    for (int kh = 0; kh < 2; ++kh) {
      __syncthreads();  // Ub free
#pragma unroll
      for (int i = 0; i < 8; ++i) {
        int row = i * 16 + srow;
        gl16(Bs + ((size_t)b * 512 + kt * 128 + row) * 256 + kh * 128 +
                 ((slc ^ (row & 15)) << 3),
             Ub + i * 2048 + wave * 512);
      }
      __syncthreads();
#pragma unroll
      for (int kk = 0; kk < 4; ++kk) {
        short8 bfr[4];
#pragma unroll
        for (int nt = 0; nt < 4; ++nt) {
          int rr = wn * 64 + nt * 16 + l16;
          bfr[nt] = *(const short8*)&Ub[rr * 128 + (((kk * 4 + quad) ^ (rr & 15)) << 3)];
        }
#pragma unroll
        for (int nt = 0; nt < 4; ++nt)
          s[kt][nt] = MFMA(af[kh * 4 + kk], bfr[nt], s[kt][nt], 0, 0, 0);
      }
    }
  }

  // ---- exact softmax ----
  const int rbase = wm * 16 + quad * 4;
  float mt[4];
#pragma unroll
  for (int r = 0; r < 4; ++r) {
    float mv = -1e30f;
#pragma unroll
    for (int kt = 0; kt < 4; ++kt)
#pragma unroll
      for (int nt = 0; nt < 4; ++nt) mv = fmaxf(mv, s[kt][nt][r]);
#pragma unroll
    for (int off = 1; off < 16; off <<= 1) mv = fmaxf(mv, __shfl_xor(mv, off));
    mt[r] = mv;
  }
  if (l16 == 0) {
#pragma unroll
    for (int r = 0; r < 4; ++r) redm[wn][rbase + r] = mt[r];
  }
  __syncthreads();
  float lsum[4];
#pragma unroll
  for (int r = 0; r < 4; ++r) {
    float mfull = fmaxf(mt[r], redm[1 ^ wn][rbase + r]);
    float sum = 0.f;
#pragma unroll
    for (int kt = 0; kt < 4; ++kt)
#pragma unroll
      for (int nt = 0; nt < 4; ++nt) {
        float p = __expf(s[kt][nt][r] - mfull);
        s[kt][nt][r] = p;
        sum += p;
      }
#pragma unroll
    for (int off = 1; off < 16; off <<= 1) sum += __shfl_xor(sum, off);
    lsum[r] = sum;
  }
  if (l16 == 0) {
#pragma unroll
    for (int r = 0; r < 4; ++r) reds[wn][rbase + r] = lsum[r];
  }
  __syncthreads();
  float linv[4];
#pragma unroll
  for (int r = 0; r < 4; ++r)
    linv[r] = 1.0f / (lsum[r] + reds[1 ^ wn][rbase + r]);

  // ---- PV ----
  f32x4 oacc[4];
#pragma unroll
  for (int nt = 0; nt < 4; ++nt) oacc[nt] = (f32x4){0.f, 0.f, 0.f, 0.f};
#pragma unroll
  for (int vt = 0; vt < 4; ++vt) {
    __syncthreads();  // Ub + Pp free
#pragma unroll
    for (int nt = 0; nt < 4; ++nt) {
      const int col = wn * 64 + nt * 16 + l16;
#pragma unroll
      for (int r = 0; r < 4; ++r) {
        const int row = rbase + r;
        Pp[row * 128 + (((col >> 3) ^ (row & 15)) << 3) + (col & 7)] =
            f2bf(s[vt][nt][r]);
      }
    }
#pragma unroll
    for (int i = 0; i < 8; ++i) {
      int row = i * 16 + srow;
      gl16(vT + ((size_t)b * 128 + row) * 512 + vt * 128 +
               ((slc ^ (row & 15)) << 3),
           Ub + i * 2048 + wave * 512);
    }
    __syncthreads();
#pragma unroll
    for (int kk = 0; kk < 4; ++kk) {
      const int prow = wm * 16 + l16;
      short8 pa = *(const short8*)&Pp[prow * 128 + (((kk * 4 + quad) ^ (prow & 15)) << 3)];
#pragma unroll
      for (int nt = 0; nt < 4; ++nt) {
        int rr = wn * 64 + nt * 16 + l16;
        short8 vb = *(const short8*)&Ub[rr * 128 + (((kk * 4 + quad) ^ (rr & 15)) << 3)];
        oacc[nt] = MFMA(pa, vb, oacc[nt], 0, 0, 0);
      }
    }
  }
#pragma unroll
  for (int nt = 0; nt < 4; ++nt) {
    const int col = wn * 64 + nt * 16 + l16;
#pragma unroll
    for (int r = 0; r < 4; ++r)
      agg[(tok0 + rbase + r) * 128 + col] = f2bf(oacc[nt][r] * linv[r]);
  }
}

// ---------------- x-GEMM (128x128 tile) + fused heads, x stays in LDS ----------------
__global__ __launch_bounds__(256, 2) void xh_gemm(
    const unsigned short* __restrict__ enc, const unsigned short* __restrict__ agg,
    const unsigned short* __restrict__ WpT, const float* __restrict__ bp,
    const unsigned short* __restrict__ WaCrT, float* __restrict__ logits,
    float* __restrict__ value) {
  __shared__ unsigned short sm[16384];  // A: [0,8192) B: [8192,16384); xs: all
  unsigned short* Asr = sm;
  unsigned short* Bsr = sm + 8192;
  const int tid = threadIdx.x, lane = tid & 63, wave = tid >> 6;
  const int quad = lane >> 4, l16 = lane & 15;
  const int wm = wave & 1, wn = wave >> 1;
  const int bm = blockIdx.y * 128, bn = blockIdx.x * 128;
  const int srow = tid >> 3, slc = tid & 7;

  f32x4 acc[4][4];
#pragma unroll
  for (int i = 0; i < 4; ++i)
#pragma unroll
    for (int j = 0; j < 4; ++j) acc[i][j] = (f32x4){0.f, 0.f, 0.f, 0.f};

  for (int kt = 0; kt < 384; kt += 64) {
    const unsigned short* Ap;
    int lda, kloc;
    if (kt < 256) { Ap = enc; lda = 256; kloc = kt; }
    else          { Ap = agg; lda = 128; kloc = kt - 256; }
#pragma unroll
    for (int i = 0; i < 4; ++i) {
      int row = i * 32 + srow;
      gl16(Ap + (size_t)(bm + row) * lda + kloc + ((slc ^ (row & 7)) << 3),
           Asr + i * 2048 + wave * 512);
      gl16(WpT + (size_t)(bn + row) * 384 + kt + ((slc ^ (row & 7)) << 3),
           Bsr + i * 2048 + wave * 512);
    }
    __syncthreads();
#pragma unroll
    for (int ks = 0; ks < 2; ++ks) {
      short8 af[4], bf[4];
#pragma unroll
      for (int mi = 0; mi < 4; ++mi) {
        int row = wm * 64 + mi * 16 + l16;
        af[mi] = *(const short8*)&Asr[row * 64 + (((ks * 4 + quad) ^ (row & 7)) << 3)];
      }
#pragma unroll
      for (int ni = 0; ni < 4; ++ni) {
        int row = wn * 64 + ni * 16 + l16;
        bf[ni] = *(const short8*)&Bsr[row * 64 + (((ks * 4 + quad) ^ (row & 7)) << 3)];
      }
#pragma unroll
      for (int mi = 0; mi < 4; ++mi)
#pragma unroll
        for (int ni = 0; ni < 4; ++ni)
          acc[mi][ni] = MFMA(af[mi], bf[ni], acc[mi][ni], 0, 0, 0);
    }
    __syncthreads();
  }

  // relu(x) tile -> LDS (rows 128 shorts, swizzle ^(row&15))
#pragma unroll
  for (int mi = 0; mi < 4; ++mi) {
    const int row = wm * 64 + mi * 16 + quad * 4;
#pragma unroll
    for (int ni = 0; ni < 4; ++ni) {
      const int colc = wn * 64 + ni * 16 + l16;
      const float bv = bp[bn + colc];
#pragma unroll
      for (int r = 0; r < 4; ++r) {
        float v = fmaxf(acc[mi][ni][r] + bv, 0.f);
        sm[(row + r) * 128 + (((colc >> 3) ^ ((row + r) & 15)) << 3) + (colc & 7)] =
            f2bf(v);
      }
    }
  }
  __syncthreads();

  // heads: partial (this block's 128 k-cols) -> atomicAdd
  f32x4 h[2][2];
#pragma unroll
  for (int i = 0; i < 2; ++i)
#pragma unroll
    for (int j = 0; j < 2; ++j) h[i][j] = (f32x4){0.f, 0.f, 0.f, 0.f};
#pragma unroll
  for (int kc = 0; kc < 4; ++kc) {
    short8 xa[2], wb[2];
#pragma unroll
    for (int hm = 0; hm < 2; ++hm) {
      int row = wave * 32 + hm * 16 + l16;
      xa[hm] = *(const short8*)&sm[row * 128 + (((kc * 4 + quad) ^ (row & 15)) << 3)];
    }
#pragma unroll
    for (int hn = 0; hn < 2; ++hn)
      wb[hn] = ld8(WaCrT + (size_t)(hn * 16 + l16) * 256 + bn + kc * 32 + quad * 8);
#pragma unroll
    for (int hm = 0; hm < 2; ++hm)
#pragma unroll
      for (int hn = 0; hn < 2; ++hn)
        h[hm][hn] = MFMA(xa[hm], wb[hn], h[hm][hn], 0, 0, 0);
  }
#pragma unroll
  for (int hm = 0; hm < 2; ++hm) {
#pragma unroll
    for (int hn = 0; hn < 2; ++hn) {
      const int n = hn * 16 + l16;
#pragma unroll
      for (int r = 0; r < 4; ++r) {
        const int grow = bm + wave * 32 + hm * 16 + quad * 4 + r;
        if (n < 16)
          atomicAdd(&logits[(size_t)grow * 16 + n], h[hm][hn][r]);
        else if (n == 16)
          atomicAdd(&value[grow], h[hm][hn][r]);
      }
    }
  }
}

// ---------------------------------------------------------------------------
extern "C" void kernel_launch(void* const* d_in, const int* in_sizes, int n_in,
                              void* d_out, int out_size, void* d_ws,
                              size_t ws_size, hipStream_t stream) {
  const float* obs = (const float*)d_in[0];
  const float* We = (const float*)d_in[2];
  const float* be = (const float*)d_in[3];
  const float* Wc = (const float*)d_in[4];
  const float* bc = (const float*)d_in[5];
  const float* Wn = (const float*)d_in[6];
  const float* bn = (const float*)d_in[7];
  const float* Wb = (const float*)d_in[8];
  const float* bb = (const float*)d_in[9];
  const float* Wi = (const float*)d_in[10];
  const float* bi = (const float*)d_in[11];
  const float* Wq = (const float*)d_in[12];
  const float* bq = (const float*)d_in[13];
  const float* Wk = (const float*)d_in[14];
  const float* bk = (const float*)d_in[15];
  const float* Wv = (const float*)d_in[16];
  const float* bv = (const float*)d_in[17];
  const float* Wp = (const float*)d_in[18];
  const float* bp = (const float*)d_in[19];
  const float* Wa = (const float*)d_in[20];
  const float* ba = (const float*)d_in[21];
  const float* Wcr = (const float*)d_in[22];
  const float* bcr = (const float*)d_in[23];

  char* base = (char*)d_ws;
  unsigned short* enc_bf = (unsigned short*)(base);              // 16.78 MB
  unsigned short* As     = (unsigned short*)(base + 16777216);   // 16.78 MB
  unsigned short* Bs     = (unsigned short*)(base + 33554432);   // 16.78 MB
  unsigned short* obsagg = (unsigned short*)(base + 50331648);   // 8.39 MB (obs_bf -> agg)
  unsigned short* msg_bf = (unsigned short*)(base + 58720256);   // 8.39 MB
  unsigned short* vT     = (unsigned short*)(base + 75497472);   // 8.39 MB
  float* imp_raw         = (float*)(base + 83886080);            // 128 KB
  unsigned short* WeT    = (unsigned short*)(base + 84148224);   // 64 KB
  unsigned short* Wmq    = (unsigned short*)(base + 84213760);   // 128 KB
  unsigned short* Wkv    = (unsigned short*)(base + 84344832);   // 64 KB
  unsigned short* WpT    = (unsigned short*)(base + 84410368);   // 192 KB
  float* bmb             = (float*)(base + 84606976);            // 512 B
  unsigned short* WaCrT  = (unsigned short*)(base + 84607488);   // 16 KB

  float* logits = (float*)d_out;
  float* value = (float*)d_out + 524288;

  prep_all<<<11425, 256, 0, stream>>>(obs, We, Wq, Wk, Wv, Wp, Wc, Wn, Wb, bc,
                                      bn, bb, Wa, Wcr, ba, bcr, WeT, Wmq, Wkv,
                                      WpT, WaCrT, bmb, obsagg, As, Bs, logits,
                                      value, imp_raw);

  // enc = relu(obs @ We + be); imp_raw += enc . Wi (atomics)
  gemm_t<1, 1, 1><<<dim3(2, 256), 256, 0, stream>>>(
      obsagg, 128, 128, nullptr, 0, 128, WeT, 128, be, be, nullptr, nullptr,
      0.f, Wi, imp_raw, enc_bf, 256, enc_bf, 256, 256);
  // msg | q*imp*rsqrtD -> As[:,0:128]
  gemm_t<0, 2, 0><<<dim3(2, 256), 256, 0, stream>>>(
      enc_bf, 256, 256, nullptr, 0, 256, Wmq, 256, bmb, bq, imp_raw, bi,
      RSQRT_D, nullptr, nullptr, msg_bf, 128, As, 256, 128);
  // k*imp -> Bs[:,0:128] | v -> vT (transposed)
  gemm_t<2, 3, 0><<<dim3(2, 256), 256, 0, stream>>>(
      msg_bf, 128, 128, nullptr, 0, 128, Wkv, 128, bk, bv, imp_raw, bi, 1.0f,
      nullptr, nullptr, Bs, 256, vT, 0, 128);

  flash4<<<1024, 256, 0, stream>>>(As, Bs, vT, obsagg);

  xh_gemm<<<dim3(2, 256), 256, 0, stream>>>(enc_bf, obsagg, WpT, bp, WaCrT,
                                            logits, value);
}

// Round 7
// 189.144 us; speedup vs baseline: 1.4747x; 1.0556x over previous
//
#include <hip/hip_runtime.h>
#include <math.h>

// ---------------------------------------------------------------------------
// HADCommNetwork forward — async-staged MFMA, composite-weight version.
// B=64, N=512, OBS=128, H=256, M=128, ACT=16, T=32768.
// Identity used: msg has no activation and only feeds K,V =>
//   K = enc@(Wm·Wk)+(bm·Wk+bk), V = enc@(Wm·Wv)+(bm·Wv+bv)  (msg eliminated).
// 6 launches: prep_all | prep_wprod | enc(+imp) | qkv | flash4 | x+heads
// ---------------------------------------------------------------------------

typedef __attribute__((ext_vector_type(8))) short short8;
typedef __attribute__((ext_vector_type(4))) float f32x4;

#define RSQRT_D 0.08838834764831843f  // 1/sqrt(128)
#define MFMA __builtin_amdgcn_mfma_f32_16x16x32_bf16

__device__ __forceinline__ unsigned short f2bf(float f) {
  union { float f; unsigned u; } v; v.f = f;
  return (unsigned short)((v.u + 0x7FFFu + ((v.u >> 16) & 1u)) >> 16);
}
__device__ __forceinline__ float bf2f(unsigned short h) {
  union { unsigned u; float f; } v; v.u = ((unsigned)h) << 16;
  return v.f;
}
__device__ __forceinline__ unsigned pack2(float a, float b) {
  return (unsigned)f2bf(a) | ((unsigned)f2bf(b) << 16);
}
__device__ __forceinline__ short8 ld8(const unsigned short* p) {
  return *(const short8*)p;
}
__device__ __forceinline__ void gl16(const unsigned short* g,
                                     unsigned short* l) {
  __builtin_amdgcn_global_load_lds(
      (const __attribute__((address_space(1))) unsigned int*)(const void*)g,
      (__attribute__((address_space(3))) unsigned int*)(void*)l, 16, 0, 0);
}

// ---------------- prep: weights + obs + output init ----------------
__global__ __launch_bounds__(256) void prep_all(
    const float* __restrict__ obs, const float* __restrict__ We,
    const float* __restrict__ Wq, const float* __restrict__ Wk,
    const float* __restrict__ Wv, const float* __restrict__ Wp,
    const float* __restrict__ Wc, const float* __restrict__ Wn,
    const float* __restrict__ Wb, const float* __restrict__ bc,
    const float* __restrict__ bn, const float* __restrict__ bb,
    const float* __restrict__ Wa, const float* __restrict__ Wcr,
    const float* __restrict__ ba, const float* __restrict__ bcr,
    const float* __restrict__ bq, unsigned short* __restrict__ WeT,
    unsigned short* __restrict__ Wqkv, unsigned short* __restrict__ Wkv,
    unsigned short* __restrict__ Wm_nt, unsigned short* __restrict__ WpT,
    unsigned short* __restrict__ WaCrT, float* __restrict__ bm,
    float* __restrict__ bqkv, unsigned short* __restrict__ obs_bf,
    unsigned short* __restrict__ As, unsigned short* __restrict__ Bs,
    float* __restrict__ logits, float* __restrict__ value,
    float* __restrict__ imp_raw) {
  const int bid = blockIdx.x, tid = threadIdx.x;
  if (bid < 929) {
    int idx = bid * 256 + tid;
    if (idx < 32768) {                 // WeT[n 256][k 128]
      int n = idx >> 7, k = idx & 127;
      WeT[idx] = f2bf(We[k * 256 + n]);
    } else if (idx < 65536) {          // Wqkv rows 0..127: WqT[n 128][k 256]
      int i = idx - 32768;
      int n = i >> 8, k = i & 255;
      Wqkv[i] = f2bf(Wq[k * 128 + n]);
    } else if (idx < 98304) {          // Wkv[n 256][k 128] = [WkT; WvT]
      int i = idx - 65536;
      int n = i >> 7, k = i & 127;
      Wkv[i] = f2bf(n < 128 ? Wk[k * 128 + n] : Wv[k * 128 + (n - 128)]);
    } else if (idx < 131072) {         // Wm_nt[h 256][m 128] (packed Wm)
      int i = idx - 98304;
      int h = i >> 7, m = i & 127;
      float v = (m < 32)   ? Wc[h * 32 + m]
              : (m < 96)   ? Wn[h * 64 + (m - 32)]
                           : Wb[h * 32 + (m - 96)];
      Wm_nt[i] = f2bf(v);
    } else if (idx < 229376) {         // WpT[n 256][k 384]
      int i = idx - 131072;
      int n = i / 384, k = i - n * 384;
      WpT[i] = f2bf(Wp[k * 256 + n]);
    } else if (idx < 237568) {         // WaCrT[32][256]
      int i = idx - 229376;
      int n = i >> 8, k = i & 255;
      float v = (n < 16) ? Wa[k * 16 + n] : (n == 16) ? Wcr[k] : 0.f;
      WaCrT[i] = f2bf(v);
    } else if (idx < 237696) {
      int i = idx - 237568;
      bm[i] = (i < 32) ? bc[i] : (i < 96) ? bn[i - 32] : bb[i - 96];
    } else if (idx < 237824) {
      int i = idx - 237696;
      bqkv[i] = bq[i];
    }
  } else if (bid < 2977) {
    // obs prep: 16 tokens/block (4 per wave)
    const int wave = tid >> 6, lane = tid & 63;
    const int t0 = (bid - 929) * 16 + wave * 4;
#pragma unroll
    for (int it = 0; it < 4; ++it) {
      int t = t0 + it;
      const float* row = obs + (size_t)t * 128;
      float2 o = *(const float2*)(row + lane * 2);
      float s2 = o.x * o.x + o.y * o.y;
#pragma unroll
      for (int off = 1; off < 64; off <<= 1) s2 += __shfl_xor(s2, off);
      float inv = 1.f / (sqrtf(s2) + 1e-8f);
      ((unsigned*)obs_bf)[(size_t)t * 64 + lane] = pack2(o.x, o.y);
      ((unsigned*)As)[(size_t)t * 128 + 64 + lane] =
          pack2(o.x * 0.5f * inv, o.y * 0.5f * inv);
      ((unsigned*)Bs)[(size_t)t * 128 + 64 + lane] =
          pack2(o.x * inv, o.y * inv);
    }
  } else if (bid < 5153) {
    int i = (bid - 2977) * 256 + tid;
    if (i < 524288) logits[i] = ba[i & 15];
    else value[i - 524288] = bcr[0];
  } else {
    imp_raw[(bid - 5153) * 256 + tid] = 0.f;
  }
}

// ---------------- composite weights: Wqkv rows 128..383 + bqkv ----------------
// C[i][h] = sum_m Wkv[i][m] * Wm_nt[h][m]  (i<128 -> WmkT, i>=128 -> WmvT)
__global__ __launch_bounds__(256) void prep_wprod(
    const unsigned short* __restrict__ Wkv,
    const unsigned short* __restrict__ Wm_nt, const float* __restrict__ bm,
    const float* __restrict__ bk, const float* __restrict__ bv,
    unsigned short* __restrict__ Wqkv, float* __restrict__ bqkv) {
  const int bid = blockIdx.x, tid = threadIdx.x;
  if (bid < 8) {
    const int lane = tid & 63, wave = tid >> 6;
    const int quad = lane >> 4, l16 = lane & 15;
    const int r0 = bid * 32;
    f32x4 acc[2][4];
#pragma unroll
    for (int i = 0; i < 2; ++i)
#pragma unroll
      for (int j = 0; j < 4; ++j) acc[i][j] = (f32x4){0.f, 0.f, 0.f, 0.f};
#pragma unroll
    for (int kc = 0; kc < 4; ++kc) {
      short8 af[2], bf[4];
#pragma unroll
      for (int i = 0; i < 2; ++i)
        af[i] = ld8(Wkv + (size_t)(r0 + i * 16 + l16) * 128 + kc * 32 + quad * 8);
#pragma unroll
      for (int j = 0; j < 4; ++j)
        bf[j] = ld8(Wm_nt + (size_t)(wave * 64 + j * 16 + l16) * 128 + kc * 32 +
                    quad * 8);
#pragma unroll
      for (int i = 0; i < 2; ++i)
#pragma unroll
        for (int j = 0; j < 4; ++j)
          acc[i][j] = MFMA(af[i], bf[j], acc[i][j], 0, 0, 0);
    }
#pragma unroll
    for (int i = 0; i < 2; ++i) {
      const int row = r0 + i * 16 + quad * 4;
#pragma unroll
      for (int j = 0; j < 4; ++j) {
        const int col = wave * 64 + j * 16 + l16;
#pragma unroll
        for (int r = 0; r < 4; ++r)
          Wqkv[(size_t)(128 + row + r) * 256 + col] = f2bf(acc[i][j][r]);
      }
    }
  } else {
    // bias: bqkv[128+i] = dot(Wkv[i][:], bm) + (bk|bv)
    int i = tid;
    float acc = (i < 128) ? bk[i] : bv[i - 128];
    for (int m = 0; m < 128; ++m)
      acc += bm[m] * bf2f(Wkv[(size_t)i * 128 + m]);
    bqkv[128 + i] = acc;
  }
}

// ---------------- enc = relu(obs @ We + be), BK=128 single phase, +imp ----------------
// grid (2, 256): 128x128 tiles. LDS rows 128 shorts (16 chunks), swizzle ^(row&15).
__global__ __launch_bounds__(256, 2) void enc_gemm(
    const unsigned short* __restrict__ obs_bf,
    const unsigned short* __restrict__ WeT, const float* __restrict__ be,
    const float* __restrict__ Wi, unsigned short* __restrict__ enc,
    float* __restrict__ imp_raw) {
  __shared__ unsigned short Asr[16384];
  __shared__ unsigned short Bsr[16384];
  const int tid = threadIdx.x, lane = tid & 63, wave = tid >> 6;
  const int quad = lane >> 4, l16 = lane & 15;
  const int wm = wave & 1, wn = wave >> 1;
  const int bm0 = blockIdx.y * 128, bn0 = blockIdx.x * 128;

  // stage A and B: 2048 16B-chunks each, 8 gl16 per thread per matrix
#pragma unroll
  for (int it = 0; it < 8; ++it) {
    int c = it * 256 + tid;
    int row = c >> 4, ch = c & 15;
    gl16(obs_bf + (size_t)(bm0 + row) * 128 + ((ch ^ (row & 15)) << 3),
         Asr + it * 2048 + wave * 512);
    gl16(WeT + (size_t)(bn0 + row) * 128 + ((ch ^ (row & 15)) << 3),
         Bsr + it * 2048 + wave * 512);
  }
  __syncthreads();

  f32x4 acc[4][4];
#pragma unroll
  for (int i = 0; i < 4; ++i)
#pragma unroll
    for (int j = 0; j < 4; ++j) acc[i][j] = (f32x4){0.f, 0.f, 0.f, 0.f};
#pragma unroll
  for (int ks = 0; ks < 4; ++ks) {
    short8 af[4], bf[4];
#pragma unroll
    for (int mi = 0; mi < 4; ++mi) {
      int row = wm * 64 + mi * 16 + l16;
      af[mi] = *(const short8*)&Asr[row * 128 + (((ks * 4 + quad) ^ (row & 15)) << 3)];
    }
#pragma unroll
    for (int ni = 0; ni < 4; ++ni) {
      int row = wn * 64 + ni * 16 + l16;
      bf[ni] = *(const short8*)&Bsr[row * 128 + (((ks * 4 + quad) ^ (row & 15)) << 3)];
    }
#pragma unroll
    for (int mi = 0; mi < 4; ++mi)
#pragma unroll
      for (int ni = 0; ni < 4; ++ni)
        acc[mi][ni] = MFMA(af[mi], bf[ni], acc[mi][ni], 0, 0, 0);
  }

#pragma unroll
  for (int mi = 0; mi < 4; ++mi) {
    const int rowb = bm0 + wm * 64 + mi * 16 + quad * 4;
    float ip[4] = {0.f, 0.f, 0.f, 0.f};
#pragma unroll
    for (int ni = 0; ni < 4; ++ni) {
      const int col = bn0 + wn * 64 + ni * 16 + l16;
      const float bv = be[col], wv = Wi[col];
#pragma unroll
      for (int r = 0; r < 4; ++r) {
        float v = fmaxf(acc[mi][ni][r] + bv, 0.f);
        enc[(size_t)(rowb + r) * 256 + col] = f2bf(v);
        ip[r] += v * wv;
      }
    }
#pragma unroll
    for (int r = 0; r < 4; ++r) {
#pragma unroll
      for (int off = 1; off < 16; off <<= 1) ip[r] += __shfl_xor(ip[r], off);
    }
    if (l16 == 0) {
#pragma unroll
      for (int r = 0; r < 4; ++r) atomicAdd(&imp_raw[rowb + r], ip[r]);
    }
  }
}

// ---------------- qkv GEMM: enc @ Wqkv (N=384, K=256), tri-epilogue ----------------
// grid (3, 256). bn 0 -> As (q * sg * rsqrtD), 1 -> Bs (k * sg), 2 -> vT.
__global__ __launch_bounds__(256, 2) void qkv_gemm(
    const unsigned short* __restrict__ enc, const unsigned short* __restrict__ Wqkv,
    const float* __restrict__ bqkv, const float* __restrict__ imp_raw,
    const float* __restrict__ bi, unsigned short* __restrict__ As,
    unsigned short* __restrict__ Bs, unsigned short* __restrict__ vT) {
  __shared__ unsigned short Asr[8192];
  __shared__ unsigned short Bsr[8192];
  const int tid = threadIdx.x, lane = tid & 63, wave = tid >> 6;
  const int quad = lane >> 4, l16 = lane & 15;
  const int wm = wave & 1, wn = wave >> 1;
  const int bx = blockIdx.x;
  const int bm0 = blockIdx.y * 128, bn0 = bx * 128;
  const int srow = tid >> 3, slc = tid & 7;

  f32x4 acc[4][4];
#pragma unroll
  for (int i = 0; i < 4; ++i)
#pragma unroll
    for (int j = 0; j < 4; ++j) acc[i][j] = (f32x4){0.f, 0.f, 0.f, 0.f};

  for (int kt = 0; kt < 256; kt += 64) {
#pragma unroll
    for (int i = 0; i < 4; ++i) {
      int row = i * 32 + srow;
      gl16(enc + (size_t)(bm0 + row) * 256 + kt + ((slc ^ (row & 7)) << 3),
           Asr + i * 2048 + wave * 512);
      gl16(Wqkv + (size_t)(bn0 + row) * 256 + kt + ((slc ^ (row & 7)) << 3),
           Bsr + i * 2048 + wave * 512);
    }
    __syncthreads();
#pragma unroll
    for (int ks = 0; ks < 2; ++ks) {
      short8 af[4], bf[4];
#pragma unroll
      for (int mi = 0; mi < 4; ++mi) {
        int row = wm * 64 + mi * 16 + l16;
        af[mi] = *(const short8*)&Asr[row * 64 + (((ks * 4 + quad) ^ (row & 7)) << 3)];
      }
#pragma unroll
      for (int ni = 0; ni < 4; ++ni) {
        int row = wn * 64 + ni * 16 + l16;
        bf[ni] = *(const short8*)&Bsr[row * 64 + (((ks * 4 + quad) ^ (row & 7)) << 3)];
      }
#pragma unroll
      for (int mi = 0; mi < 4; ++mi)
#pragma unroll
        for (int ni = 0; ni < 4; ++ni)
          acc[mi][ni] = MFMA(af[mi], bf[ni], acc[mi][ni], 0, 0, 0);
    }
    __syncthreads();
  }

  const float bi0 = bi[0];
#pragma unroll
  for (int mi = 0; mi < 4; ++mi) {
    const int rowb = bm0 + wm * 64 + mi * 16 + quad * 4;
    float sg[4];
    if (bx < 2) {
      const float mult = (bx == 0) ? RSQRT_D : 1.0f;
#pragma unroll
      for (int r = 0; r < 4; ++r)
        sg[r] = mult / (1.f + __expf(-(imp_raw[rowb + r] + bi0)));
    }
#pragma unroll
    for (int ni = 0; ni < 4; ++ni) {
      const int col = wn * 64 + ni * 16 + l16;  // 0..127 local
      const float bv = bqkv[bx * 128 + col];
      if (bx == 0) {
#pragma unroll
        for (int r = 0; r < 4; ++r)
          As[(size_t)(rowb + r) * 256 + col] = f2bf((acc[mi][ni][r] + bv) * sg[r]);
      } else if (bx == 1) {
#pragma unroll
        for (int r = 0; r < 4; ++r)
          Bs[(size_t)(rowb + r) * 256 + col] = f2bf((acc[mi][ni][r] + bv) * sg[r]);
      } else {
        uint2 o;
        o.x = pack2(acc[mi][ni][0] + bv, acc[mi][ni][1] + bv);
        o.y = pack2(acc[mi][ni][2] + bv, acc[mi][ni][3] + bv);
        *(uint2*)(vT + ((size_t)(rowb >> 9) * 128 + col) * 512 + (rowb & 511)) = o;
      }
    }
  }
}

// ---------------- flash4: async-staged, single-pass softmax (unchanged) ----------------
__global__ __launch_bounds__(256, 3) void flash4(
    const unsigned short* __restrict__ As, const unsigned short* __restrict__ Bs,
    const unsigned short* __restrict__ vT, unsigned short* __restrict__ agg) {
  __shared__ unsigned short Ub[16384];  // 32 KB
  __shared__ unsigned short Pp[4096];   // 8 KB
  __shared__ float redm[2][32];
  __shared__ float reds[2][32];
  const int tid = threadIdx.x, lane = tid & 63, wave = tid >> 6;
  const int quad = lane >> 4, l16 = lane & 15;
  const int wm = wave & 1, wn = wave >> 1;
  const int b = blockIdx.x & 63;
  const int qt = blockIdx.x >> 6;
  const size_t tok0 = (size_t)b * 512 + qt * 32;
  const int srow = tid >> 4, slc = tid & 15;

  short8 af[8];
#pragma unroll
  for (int kc = 0; kc < 8; ++kc)
    af[kc] = ld8(As + (tok0 + wm * 16 + l16) * 256 + kc * 32 + quad * 8);

  f32x4 s[4][4];
#pragma unroll
  for (int kt = 0; kt < 4; ++kt)
#pragma unroll
    for (int nt = 0; nt < 4; ++nt) s[kt][nt] = (f32x4){0.f, 0.f, 0.f, 0.f};

#pragma unroll
  for (int kt = 0; kt < 4; ++kt) {
#pragma unroll
    for (int kh = 0; kh < 2; ++kh) {
      __syncthreads();
#pragma unroll
      for (int i = 0; i < 8; ++i) {
        int row = i * 16 + srow;
        gl16(Bs + ((size_t)b * 512 + kt * 128 + row) * 256 + kh * 128 +
                 ((slc ^ (row & 15)) << 3),
             Ub + i * 2048 + wave * 512);
      }
      __syncthreads();
#pragma unroll
      for (int kk = 0; kk < 4; ++kk) {
        short8 bfr[4];
#pragma unroll
        for (int nt = 0; nt < 4; ++nt) {
          int rr = wn * 64 + nt * 16 + l16;
          bfr[nt] = *(const short8*)&Ub[rr * 128 + (((kk * 4 + quad) ^ (rr & 15)) << 3)];
        }
#pragma unroll
        for (int nt = 0; nt < 4; ++nt)
          s[kt][nt] = MFMA(af[kh * 4 + kk], bfr[nt], s[kt][nt], 0, 0, 0);
      }
    }
  }

  const int rbase = wm * 16 + quad * 4;
  float mt[4];
#pragma unroll
  for (int r = 0; r < 4; ++r) {
    float mv = -1e30f;
#pragma unroll
    for (int kt = 0; kt < 4; ++kt)
#pragma unroll
      for (int nt = 0; nt < 4; ++nt) mv = fmaxf(mv, s[kt][nt][r]);
#pragma unroll
    for (int off = 1; off < 16; off <<= 1) mv = fmaxf(mv, __shfl_xor(mv, off));
    mt[r] = mv;
  }
  if (l16 == 0) {
#pragma unroll
    for (int r = 0; r < 4; ++r) redm[wn][rbase + r] = mt[r];
  }
  __syncthreads();
  float lsum[4];
#pragma unroll
  for (int r = 0; r < 4; ++r) {
    float mfull = fmaxf(mt[r], redm[1 ^ wn][rbase + r]);
    float sum = 0.f;
#pragma unroll
    for (int kt = 0; kt < 4; ++kt)
#pragma unroll
      for (int nt = 0; nt < 4; ++nt) {
        float p = __expf(s[kt][nt][r] - mfull);
        s[kt][nt][r] = p;
        sum += p;
      }
#pragma unroll
    for (int off = 1; off < 16; off <<= 1) sum += __shfl_xor(sum, off);
    lsum[r] = sum;
  }
  if (l16 == 0) {
#pragma unroll
    for (int r = 0; r < 4; ++r) reds[wn][rbase + r] = lsum[r];
  }
  __syncthreads();
  float linv[4];
#pragma unroll
  for (int r = 0; r < 4; ++r)
    linv[r] = 1.0f / (lsum[r] + reds[1 ^ wn][rbase + r]);

  f32x4 oacc[4];
#pragma unroll
  for (int nt = 0; nt < 4; ++nt) oacc[nt] = (f32x4){0.f, 0.f, 0.f, 0.f};
#pragma unroll
  for (int vt = 0; vt < 4; ++vt) {
    __syncthreads();
#pragma unroll
    for (int nt = 0; nt < 4; ++nt) {
      const int col = wn * 64 + nt * 16 + l16;
#pragma unroll
      for (int r = 0; r < 4; ++r) {
        const int row = rbase + r;
        Pp[row * 128 + (((col >> 3) ^ (row & 15)) << 3) + (col & 7)] =
            f2bf(s[vt][nt][r]);
      }
    }
#pragma unroll
    for (int i = 0; i < 8; ++i) {
      int row = i * 16 + srow;
      gl16(vT + ((size_t)b * 128 + row) * 512 + vt * 128 +
               ((slc ^ (row & 15)) << 3),
           Ub + i * 2048 + wave * 512);
    }
    __syncthreads();
#pragma unroll
    for (int kk = 0; kk < 4; ++kk) {
      const int prow = wm * 16 + l16;
      short8 pa = *(const short8*)&Pp[prow * 128 + (((kk * 4 + quad) ^ (prow & 15)) << 3)];
#pragma unroll
      for (int nt = 0; nt < 4; ++nt) {
        int rr = wn * 64 + nt * 16 + l16;
        short8 vb = *(const short8*)&Ub[rr * 128 + (((kk * 4 + quad) ^ (rr & 15)) << 3)];
        oacc[nt] = MFMA(pa, vb, oacc[nt], 0, 0, 0);
      }
    }
  }
#pragma unroll
  for (int nt = 0; nt < 4; ++nt) {
    const int col = wn * 64 + nt * 16 + l16;
#pragma unroll
    for (int r = 0; r < 4; ++r)
      agg[(tok0 + rbase + r) * 128 + col] = f2bf(oacc[nt][r] * linv[r]);
  }
}

// ---------------- x-GEMM (128x128) + fused heads (unchanged) ----------------
__global__ __launch_bounds__(256, 2) void xh_gemm(
    const unsigned short* __restrict__ enc, const unsigned short* __restrict__ agg,
    const unsigned short* __restrict__ WpT, const float* __restrict__ bp,
    const unsigned short* __restrict__ WaCrT, float* __restrict__ logits,
    float* __restrict__ value) {
  __shared__ unsigned short sm[16384];
  unsigned short* Asr = sm;
  unsigned short* Bsr = sm + 8192;
  const int tid = threadIdx.x, lane = tid & 63, wave = tid >> 6;
  const int quad = lane >> 4, l16 = lane & 15;
  const int wm = wave & 1, wn = wave >> 1;
  const int bm = blockIdx.y * 128, bn = blockIdx.x * 128;
  const int srow = tid >> 3, slc = tid & 7;

  f32x4 acc[4][4];
#pragma unroll
  for (int i = 0; i < 4; ++i)
#pragma unroll
    for (int j = 0; j < 4; ++j) acc[i][j] = (f32x4){0.f, 0.f, 0.f, 0.f};

  for (int kt = 0; kt < 384; kt += 64) {
    const unsigned short* Ap;
    int lda, kloc;
    if (kt < 256) { Ap = enc; lda = 256; kloc = kt; }
    else          { Ap = agg; lda = 128; kloc = kt - 256; }
#pragma unroll
    for (int i = 0; i < 4; ++i) {
      int row = i * 32 + srow;
      gl16(Ap + (size_t)(bm + row) * lda + kloc + ((slc ^ (row & 7)) << 3),
           Asr + i * 2048 + wave * 512);
      gl16(WpT + (size_t)(bn + row) * 384 + kt + ((slc ^ (row & 7)) << 3),
           Bsr + i * 2048 + wave * 512);
    }
    __syncthreads();
#pragma unroll
    for (int ks = 0; ks < 2; ++ks) {
      short8 af[4], bf[4];
#pragma unroll
      for (int mi = 0; mi < 4; ++mi) {
        int row = wm * 64 + mi * 16 + l16;
        af[mi] = *(const short8*)&Asr[row * 64 + (((ks * 4 + quad) ^ (row & 7)) << 3)];
      }
#pragma unroll
      for (int ni = 0; ni < 4; ++ni) {
        int row = wn * 64 + ni * 16 + l16;
        bf[ni] = *(const short8*)&Bsr[row * 64 + (((ks * 4 + quad) ^ (row & 7)) << 3)];
      }
#pragma unroll
      for (int mi = 0; mi < 4; ++mi)
#pragma unroll
        for (int ni = 0; ni < 4; ++ni)
          acc[mi][ni] = MFMA(af[mi], bf[ni], acc[mi][ni], 0, 0, 0);
    }
    __syncthreads();
  }

#pragma unroll
  for (int mi = 0; mi < 4; ++mi) {
    const int row = wm * 64 + mi * 16 + quad * 4;
#pragma unroll
    for (int ni = 0; ni < 4; ++ni) {
      const int colc = wn * 64 + ni * 16 + l16;
      const float bv = bp[bn + colc];
#pragma unroll
      for (int r = 0; r < 4; ++r) {
        float v = fmaxf(acc[mi][ni][r] + bv, 0.f);
        sm[(row + r) * 128 + (((colc >> 3) ^ ((row + r) & 15)) << 3) + (colc & 7)] =
            f2bf(v);
      }
    }
  }
  __syncthreads();

  f32x4 h[2][2];
#pragma unroll
  for (int i = 0; i < 2; ++i)
#pragma unroll
    for (int j = 0; j < 2; ++j) h[i][j] = (f32x4){0.f, 0.f, 0.f, 0.f};
#pragma unroll
  for (int kc = 0; kc < 4; ++kc) {
    short8 xa[2], wb[2];
#pragma unroll
    for (int hm = 0; hm < 2; ++hm) {
      int row = wave * 32 + hm * 16 + l16;
      xa[hm] = *(const short8*)&sm[row * 128 + (((kc * 4 + quad) ^ (row & 15)) << 3)];
    }
#pragma unroll
    for (int hn = 0; hn < 2; ++hn)
      wb[hn] = ld8(WaCrT + (size_t)(hn * 16 + l16) * 256 + bn + kc * 32 + quad * 8);
#pragma unroll
    for (int hm = 0; hm < 2; ++hm)
#pragma unroll
      for (int hn = 0; hn < 2; ++hn)
        h[hm][hn] = MFMA(xa[hm], wb[hn], h[hm][hn], 0, 0, 0);
  }
#pragma unroll
  for (int hm = 0; hm < 2; ++hm) {
#pragma unroll
    for (int hn = 0; hn < 2; ++hn) {
      const int n = hn * 16 + l16;
#pragma unroll
      for (int r = 0; r < 4; ++r) {
        const int grow = bm + wave * 32 + hm * 16 + quad * 4 + r;
        if (n < 16)
          atomicAdd(&logits[(size_t)grow * 16 + n], h[hm][hn][r]);
        else if (n == 16)
          atomicAdd(&value[grow], h[hm][hn][r]);
      }
    }
  }
}

// ---------------------------------------------------------------------------
extern "C" void kernel_launch(void* const* d_in, const int* in_sizes, int n_in,
                              void* d_out, int out_size, void* d_ws,
                              size_t ws_size, hipStream_t stream) {
  const float* obs = (const float*)d_in[0];
  const float* We = (const float*)d_in[2];
  const float* be = (const float*)d_in[3];
  const float* Wc = (const float*)d_in[4];
  const float* bc = (const float*)d_in[5];
  const float* Wn = (const float*)d_in[6];
  const float* bn = (const float*)d_in[7];
  const float* Wb = (const float*)d_in[8];
  const float* bb = (const float*)d_in[9];
  const float* Wi = (const float*)d_in[10];
  const float* bi = (const float*)d_in[11];
  const float* Wq = (const float*)d_in[12];
  const float* bq = (const float*)d_in[13];
  const float* Wk = (const float*)d_in[14];
  const float* bk = (const float*)d_in[15];
  const float* Wv = (const float*)d_in[16];
  const float* bv = (const float*)d_in[17];
  const float* Wp = (const float*)d_in[18];
  const float* bp = (const float*)d_in[19];
  const float* Wa = (const float*)d_in[20];
  const float* ba = (const float*)d_in[21];
  const float* Wcr = (const float*)d_in[22];
  const float* bcr = (const float*)d_in[23];

  char* base = (char*)d_ws;
  unsigned short* enc_bf = (unsigned short*)(base);              // 16.78 MB
  unsigned short* As     = (unsigned short*)(base + 16777216);   // 16.78 MB
  unsigned short* Bs     = (unsigned short*)(base + 33554432);   // 16.78 MB
  unsigned short* obsagg = (unsigned short*)(base + 50331648);   // 8.39 MB (obs_bf -> agg)
  unsigned short* vT     = (unsigned short*)(base + 58720256);   // 8.39 MB
  float* imp_raw         = (float*)(base + 67108864);            // 128 KB
  unsigned short* WeT    = (unsigned short*)(base + 67239936);   // 64 KB
  unsigned short* Wqkv   = (unsigned short*)(base + 67305472);   // 192 KB
  unsigned short* Wkv    = (unsigned short*)(base + 67502080);   // 64 KB
  unsigned short* Wm_nt  = (unsigned short*)(base + 67567616);   // 64 KB
  unsigned short* WpT    = (unsigned short*)(base + 67633152);   // 192 KB
  unsigned short* WaCrT  = (unsigned short*)(base + 67829760);   // 16 KB
  float* bmb             = (float*)(base + 67846144);            // 512 B
  float* bqkv            = (float*)(base + 67846656);            // 1.5 KB

  float* logits = (float*)d_out;
  float* value = (float*)d_out + 524288;

  prep_all<<<5281, 256, 0, stream>>>(obs, We, Wq, Wk, Wv, Wp, Wc, Wn, Wb, bc,
                                     bn, bb, Wa, Wcr, ba, bcr, bq, WeT, Wqkv,
                                     Wkv, Wm_nt, WpT, WaCrT, bmb, bqkv, obsagg,
                                     As, Bs, logits, value, imp_raw);
  prep_wprod<<<9, 256, 0, stream>>>(Wkv, Wm_nt, bmb, bk, bv, Wqkv, bqkv);

  enc_gemm<<<dim3(2, 256), 256, 0, stream>>>(obsagg, WeT, be, Wi, enc_bf,
                                             imp_raw);
  qkv_gemm<<<dim3(3, 256), 256, 0, stream>>>(enc_bf, Wqkv, bqkv, imp_raw, bi,
                                             As, Bs, vT);
  flash4<<<1024, 256, 0, stream>>>(As, Bs, vT, obsagg);
  xh_gemm<<<dim3(2, 256), 256, 0, stream>>>(enc_bf, obsagg, WpT, bp, WaCrT,
                                            logits, value);
}